// Round 12
// baseline (263.170 us; speedup 1.0000x reference)
//
#include <hip/hip_runtime.h>

#define NN 1000
#define NE 64000
#define HH 256

typedef _Float16 half8 __attribute__((ext_vector_type(8)));
typedef float floatx4 __attribute__((ext_vector_type(4)));

struct PrepArgs { const float* w0[5]; const float* w1[5]; };

// ---------------------------------------------------------------------------
// Pipeline (11 dispatches; boundary ~2 µs. In-kernel cross-block sync BANNED:
// grid.sync ~110 µs (r1), threadfence flag-barrier ~115 µs (r4)).
//   1. k_pre1    : hist (16 private regions) || layer-0 node GEMM (in-kernel
//                  weight conversion) || chores (swizzles + zeroing)
//   2. k_scatter2: replicated scan + counting-sort scatter + CHUNK TABLE
//   3..11. 5 x edge_gemm4 (+ 4 x k_node interleaved)
// edge_gemm4 (r12): 256 blocks x 1024 threads (16 waves, 1/CU). Each wave
// owns a 16-col slice -> its W2 fragment = 8 KB = 32 VGPRs, loaded ONCE and
// reused across 8 chunk slots per block. W2 L2 streaming drops 188 -> 32
// MB/layer (was the dominant cost: 128 KB/block x ~1470 blocks, unhideable
// in the 32 KB L1). Staging/swizzle/MFMA order identical to r11 ->
// bit-identical numerics. Sole chunks plain-store; split chunks atomicMax.
// ---------------------------------------------------------------------------

// C = X[M,Kd] @ Wn^T, 16x128 tile per block (252 tiles); Wn in fragment order.
template <int NK>
__device__ __forceinline__ void node_tile(const float* __restrict__ X,
                                          const _Float16* __restrict__ Wn,
                                          const float* __restrict__ b0,
                                          _Float16* __restrict__ out, int bid) {
    const int Kd = NK * 32;
    int t = threadIdx.x;
    int wave = t >> 6, lane = t & 63;
    int q = lane >> 4, mn = lane & 15;
    int m0 = (bid % 63) * 16;
    int n0 = (bid / 63) * 128 + wave * 32;
    int slice = (bid / 63) * 4 + wave;
    int rr = m0 + mn;
    if (rr >= NN) rr = NN - 1;

    half8 afa[NK];
    half8 bfa[NK][2];
#pragma unroll
    for (int kk = 0; kk < NK; kk++) {
        int ka = kk * 32 + q * 8;
        const float* p = X + (size_t)rr * Kd + ka;
        floatx4 x0 = *(const floatx4*)p;
        floatx4 x1 = *(const floatx4*)(p + 4);
        half8 aa;
#pragma unroll
        for (int j = 0; j < 4; j++) { aa[j] = (_Float16)x0[j]; aa[4 + j] = (_Float16)x1[j]; }
        afa[kk] = aa;
        bfa[kk][0] = *(const half8*)(Wn + (((slice * NK + kk) * 2 + 0) * 64 + lane) * 8);
        bfa[kk][1] = *(const half8*)(Wn + (((slice * NK + kk) * 2 + 1) * 64 + lane) * 8);
    }
    floatx4 acc[2] = {};
#pragma unroll
    for (int kk = 0; kk < NK; kk++) {
        acc[0] = __builtin_amdgcn_mfma_f32_16x16x32_f16(afa[kk], bfa[kk][0], acc[0], 0, 0, 0);
        acc[1] = __builtin_amdgcn_mfma_f32_16x16x32_f16(afa[kk], bfa[kk][1], acc[1], 0, 0, 0);
    }
#pragma unroll
    for (int nt = 0; nt < 2; nt++) {
        int col = n0 + nt * 16 + mn;
        float bias = (col < 256) ? b0[col] : 0.f;
#pragma unroll
        for (int r2 = 0; r2 < 4; r2++) {
            int orow = m0 + q * 4 + r2;
            if (orow < NN)
                out[(size_t)orow * 512 + col] = (_Float16)(acc[nt][r2] + bias);
        }
    }
}

// layer-0 node GEMM with IN-KERNEL fp32->fp16 fragment conversion from w0.
__device__ __forceinline__ void node_tile0(const float* __restrict__ X,
                                           const float* __restrict__ w0,
                                           const float* __restrict__ b0,
                                           _Float16* __restrict__ out, int bid) {
    const int NK = 4;
    const int Kd = 128;
    int t = threadIdx.x;
    int wave = t >> 6, lane = t & 63;
    int q = lane >> 4, mn = lane & 15;
    int m0 = (bid % 63) * 16;
    int n0 = (bid / 63) * 128 + wave * 32;
    int slice = (bid / 63) * 4 + wave;
    int rr = m0 + mn;
    if (rr >= NN) rr = NN - 1;

    half8 afa[NK];
    half8 bfa[NK][2];
#pragma unroll
    for (int kk = 0; kk < NK; kk++) {
        int ka = kk * 32 + q * 8;
        const float* p = X + (size_t)rr * Kd + ka;
        floatx4 x0 = *(const floatx4*)p;
        floatx4 x1 = *(const floatx4*)(p + 4);
        half8 aa;
#pragma unroll
        for (int j = 0; j < 4; j++) { aa[j] = (_Float16)x0[j]; aa[4 + j] = (_Float16)x1[j]; }
        afa[kk] = aa;
#pragma unroll
        for (int nt = 0; nt < 2; nt++) {
            int n = slice * 32 + nt * 16 + mn;
            int k = kk * 32 + q * 8;
            half8 bb;
            if (n < 256) {
                const float* pa = w0 + (size_t)n * 256 + k;
                floatx4 a0 = *(const floatx4*)pa;
                floatx4 a1 = *(const floatx4*)(pa + 4);
                floatx4 c0 = *(const floatx4*)(pa + 128);
                floatx4 c1 = *(const floatx4*)(pa + 132);
#pragma unroll
                for (int j = 0; j < 4; j++) {
                    bb[j] = (_Float16)(a0[j] - c0[j]);
                    bb[4 + j] = (_Float16)(a1[j] - c1[j]);
                }
            } else {
                const float* pb = w0 + (size_t)(n - 256) * 256 + 128 + k;
                floatx4 c0 = *(const floatx4*)pb;
                floatx4 c1 = *(const floatx4*)(pb + 4);
#pragma unroll
                for (int j = 0; j < 4; j++) {
                    bb[j] = (_Float16)c0[j];
                    bb[4 + j] = (_Float16)c1[j];
                }
            }
            bfa[kk][nt] = bb;
        }
    }
    floatx4 acc[2] = {};
#pragma unroll
    for (int kk = 0; kk < NK; kk++) {
        acc[0] = __builtin_amdgcn_mfma_f32_16x16x32_f16(afa[kk], bfa[kk][0], acc[0], 0, 0, 0);
        acc[1] = __builtin_amdgcn_mfma_f32_16x16x32_f16(afa[kk], bfa[kk][1], acc[1], 0, 0, 0);
    }
#pragma unroll
    for (int nt = 0; nt < 2; nt++) {
        int col = n0 + nt * 16 + mn;
        float bias = (col < 256) ? b0[col] : 0.f;
#pragma unroll
        for (int r2 = 0; r2 < 4; r2++) {
            int orow = m0 + q * 4 + r2;
            if (orow < NN)
                out[(size_t)orow * 512 + col] = (_Float16)(acc[nt][r2] + bias);
        }
    }
}

// ONE pre dispatch: hist (16 private regions) || layer-0 node GEMM || chores.
__global__ __launch_bounds__(256) void k_pre1(PrepArgs pa,
                                              const int* __restrict__ ei,
                                              const float* __restrict__ X,
                                              const float* __restrict__ b0_0,
                                              _Float16* __restrict__ node_ab,
                                              _Float16* wnode, _Float16* w2h,
                                              int* cnts16, int* cursor,
                                              float* agg0, float* dout) {
    int bid = blockIdx.x;
    int t = threadIdx.x;
    if (bid < 16) {
        int* my = cnts16 + bid * 1024;
        for (int i = t; i < 1024; i += 256) my[i] = 0;
        __syncthreads();
        for (int e = bid * 256 + t; e < NE; e += 16 * 256)
            atomicAdd(&my[ei[NE + e] & 1023], 1);
    } else if (bid < 16 + 252) {
        node_tile0(X, pa.w0[0], b0_0, node_ab, bid - 16);
    } else {
        int gtid = (bid - 268) * 256 + t;
        int gs = 256 * 256;
        for (int i = gtid; i < 1024; i += gs) cursor[i] = 0;
        for (int l = 1; l < 5; l++) {
            const float* w0 = pa.w0[l];
            _Float16* wn = wnode + l * 131072;
            for (int i = gtid; i < 131072; i += gs) {
                int j = i & 7;
                int lane = (i >> 3) & 63;
                int nt = (i >> 9) & 1;
                int kk = (i >> 10) & 7;
                int slice = i >> 13;
                int mn = lane & 15, q = lane >> 4;
                int n = slice * 32 + nt * 16 + mn;
                int k = kk * 32 + q * 8 + j;
                float v = (n < 256) ? (w0[n * 512 + k] - w0[n * 512 + 256 + k])
                                    : w0[(n - 256) * 512 + 256 + k];
                wn[i] = (_Float16)v;
            }
        }
        for (int l = 0; l < 5; l++) {
            const float* w1 = pa.w1[l];
            _Float16* w2 = w2h + l * 65536;
            for (int i = gtid; i < 65536; i += gs) {
                int j = i & 7;
                int lane = (i >> 3) & 63;
                int nt = (i >> 9) & 3;
                int kk = (i >> 11) & 7;
                int ws = (i >> 14) & 3;
                int mn = lane & 15, q = lane >> 4;
                int row = ws * 64 + nt * 16 + mn;
                int col = kk * 32 + q * 8 + j;
                w2[i] = (_Float16)w1[row * 256 + col];
            }
        }
        floatx4 z = {0.f, 0.f, 0.f, 0.f};
        floatx4* p4 = (floatx4*)agg0;
        for (int i = gtid; i < 4 * NN * HH / 4; i += gs) p4[i] = z;
        floatx4* o4 = (floatx4*)dout;
        for (int i = gtid; i < NN * HH / 4; i += gs) o4[i] = z;
    }
}

// Replicated scan (sums 16 hist regions) + counting-sort scatter (src only).
// Block 0 additionally builds the chunk table: one int4 {dst, start, len,
// sole} per (dst, <=64 edges) chunk; tail entries zeroed (len=0).
__global__ __launch_bounds__(256) void k_scatter2(const int* __restrict__ ei,
                                                  const int* __restrict__ cnts16,
                                                  int* __restrict__ cursor,
                                                  int* __restrict__ ssrc,
                                                  int4* __restrict__ table) {
    __shared__ int sbase[1024];
    __shared__ int ssum[256];
    __shared__ int schk[256];
    int t = threadIdx.x;
    int base = t * 4;
    int c4[4]; int sum = 0;
#pragma unroll
    for (int j = 0; j < 4; j++) {
        int c = 0;
#pragma unroll
        for (int b = 0; b < 16; b++) c += cnts16[b * 1024 + base + j];
        c4[j] = c; sum += c;
    }
    ssum[t] = sum;
    // chunk counts (second scan array filled before scans run)
    int ch4[4]; int csum = 0;
#pragma unroll
    for (int j = 0; j < 4; j++) { ch4[j] = (c4[j] + 63) >> 6; csum += ch4[j]; }
    schk[t] = csum;
    __syncthreads();
    for (int d = 1; d < 256; d <<= 1) {
        int v1 = (t >= d) ? ssum[t - d] : 0;
        int v2 = (t >= d) ? schk[t - d] : 0;
        __syncthreads();
        ssum[t] += v1;
        schk[t] += v2;
        __syncthreads();
    }
    int run = (t > 0) ? ssum[t - 1] : 0;
#pragma unroll
    for (int j = 0; j < 4; j++) { sbase[base + j] = run; run += c4[j]; }
    __syncthreads();
    if (blockIdx.x == 0) {
        int crun = (t > 0) ? schk[t - 1] : 0;
#pragma unroll
        for (int j = 0; j < 4; j++) {
            int d = base + j, c = c4[j], st = sbase[base + j], nc = ch4[j];
            for (int k = 0; k < nc; k++) {
                int len = c - k * 64; if (len > 64) len = 64;
                table[crun + k] = make_int4(d, st + k * 64, len, nc == 1 ? 1 : 0);
            }
            crun += nc;
        }
        int nch = schk[255];
        for (int i = nch + t; i < 2048; i += 256) table[i] = make_int4(0, 0, 0, 0);
    }
    for (int e = blockIdx.x * 256 + t; e < NE; e += gridDim.x * 256) {
        int s = ei[e] & 1023, d = ei[NE + e] & 1023;
        int pos = sbase[d] + atomicAdd(&cursor[d], 1);
        if (pos < NE) ssrc[pos] = s;
    }
}

// pure node GEMM layer l+1 (reads agg_in), 252 blocks
__global__ __launch_bounds__(256) void k_node(const float* __restrict__ agg_in,
                                              const _Float16* __restrict__ Wn,
                                              const float* __restrict__ b0,
                                              _Float16* __restrict__ out) {
    node_tile<8>(agg_in, Wn, b0, out, blockIdx.x);
}

// r12: 1024-thread blocks (16 waves), 256 blocks (1/CU). Wave w owns cols
// w*16..w*16+15: its W2 fragment slice (8 KB) lives in 8 half8 REGISTERS,
// loaded once, reused across 8 chunk slots. Same prep layout re-indexed:
// addr = W2 + (w>>2)*16384 + (w&3)*512 + kk*2048 + lane*8.
// Per chunk: stage h1 (64x256, XOR swizzle, identical to r11) -> 8kk x 4mt
// MFMA -> masked reg-max + 2 shfl_xor over q -> relu(max+bias) -> store
// (sole: plain; split: atomicMax). Bit-identical numerics to r11.
__global__ __launch_bounds__(1024, 4) void edge_gemm4(const _Float16* __restrict__ node_ab,
                          const int* __restrict__ ssrc,
                          const int4* __restrict__ table,
                          const _Float16* __restrict__ W2,
                          const float* __restrict__ b2,
                          float* __restrict__ agg) {
    __shared__ _Float16 h1[64 * 256];
    int t = threadIdx.x;
    int wave = t >> 6, lane = t & 63;
    int q = lane >> 4, mn = lane & 15;
    int s = lane & 31;          // staging: 16-B slot within the 256-half half-row
    int rp = t >> 5;            // staging: rowpair 0..31

    const _Float16* Wb = W2 + (wave >> 2) * 16384 + (wave & 3) * 512 + (size_t)lane * 8;
    half8 w2r[8];
#pragma unroll
    for (int kk = 0; kk < 8; kk++)
        w2r[kk] = *(const half8*)(Wb + kk * 2048);
    float bias = b2[wave * 16 + mn];

    for (int i = 0; i < 8; i++) {
        int4 ck = table[blockIdx.x + i * 256];
        int len = ck.z;
        if (len == 0) continue;               // block-uniform
        int dst = ck.x, start = ck.y, sole = ck.w;

        __syncthreads();                      // protect h1 from prev chunk's readers
        {
            half8 av = *(const half8*)(node_ab + (size_t)dst * 512 + s * 8);
#pragma unroll
            for (int rr = 0; rr < 2; rr++) {
                int row = rp * 2 + rr;
                half8 hv = {};
                if (row < len) {
                    int sn = ssrc[start + row];   // 32-lane broadcast load
                    half8 bv = *(const half8*)(node_ab + (size_t)sn * 512 + 256 + s * 8);
                    hv = av + bv;
#pragma unroll
                    for (int j = 0; j < 8; j++) hv[j] = hv[j] > (_Float16)0 ? hv[j] : (_Float16)0;
                }
                int p = (s & ~7) | ((s ^ row) & 7);   // XOR swizzle, c = s
                *(half8*)(&h1[row * 256 + p * 8]) = hv;
            }
        }
        __syncthreads();

        floatx4 acc[4] = {};
#pragma unroll
        for (int kk = 0; kk < 8; kk++) {
#pragma unroll
            for (int mt = 0; mt < 4; mt++) {
                int r = mt * 16 + mn;
                int c = kk * 4 + q;
                int p = (c & ~7) | ((c ^ r) & 7);
                half8 af = *(const half8*)(&h1[r * 256 + p * 8]);
                acc[mt] = __builtin_amdgcn_mfma_f32_16x16x32_f16(af, w2r[kk], acc[mt], 0, 0, 0);
            }
        }

        float m = -3.0e38f;
#pragma unroll
        for (int mt = 0; mt < 4; mt++) {
#pragma unroll
            for (int r2 = 0; r2 < 4; r2++) {
                int row = mt * 16 + q * 4 + r2;
                if (row < len) m = fmaxf(m, acc[mt][r2]);
            }
        }
        m = fmaxf(m, __shfl_xor(m, 16, 64));
        m = fmaxf(m, __shfl_xor(m, 32, 64));
        if (q == 0) {
            float v = m + bias;
            v = v > 0.f ? v : 0.f;
            float* p = agg + (size_t)dst * HH + wave * 16 + mn;
            if (sole) {
                *p = v;                               // block-exclusive row
            } else if (v > 0.f) {
                atomicMax((unsigned int*)p, __float_as_uint(v));  // agg pre-zeroed
            }
        }
    }
}

extern "C" void kernel_launch(void* const* d_in, const int* in_sizes, int n_in,
                              void* d_out, int out_size, void* d_ws, size_t ws_size,
                              hipStream_t stream) {
    const float* x = (const float*)d_in[0];
    const int* ei = (const int*)d_in[1];  // int32 per harness contract
    PrepArgs pa;
    const float* b0s[5];
    const float* b1s[5];
    for (int l = 0; l < 5; l++) {
        pa.w0[l] = (const float*)d_in[2 + 4 * l];
        b0s[l] = (const float*)d_in[3 + 4 * l];
        pa.w1[l] = (const float*)d_in[4 + 4 * l];
        b1s[l] = (const float*)d_in[5 + 4 * l];
    }

    int* ssrc = (int*)d_ws;                              // 64000 ints
    int* cnts16 = ssrc + NE;                             // 16 x 1024 ints
    int* cursor = cnts16 + 16 * 1024;                    // 1024 ints
    int4* table = (int4*)(cursor + 1024);                // 2048 int4 (32 KB)
    _Float16* node_ab = (_Float16*)(table + 2048);       // [1024][512] fp16, 1 MB
    float* agg0 = (float*)(node_ab + 1024 * 512);        // 4 x 1 MB (contiguous)
    float* agg1 = agg0 + NN * HH;
    float* agg2 = agg1 + NN * HH;
    float* agg3 = agg2 + NN * HH;
    _Float16* wnode = (_Float16*)(agg3 + NN * HH);       // 5 x 131072 halfs (slot 0 unused)
    _Float16* w2h = wnode + 5 * 131072;                  // 5 x 65536 halfs

    hipLaunchKernelGGL(k_pre1, dim3(524), dim3(256), 0, stream,
                       pa, ei, x, b0s[0], node_ab, wnode, w2h,
                       cnts16, cursor, agg0, (float*)d_out);
    hipLaunchKernelGGL(k_scatter2, dim3(NE / 256), dim3(256), 0, stream,
                       ei, cnts16, cursor, ssrc, table);

    float* aggs[5] = {agg0, agg1, agg2, agg3, (float*)d_out};
    for (int l = 0; l < 5; l++) {
        hipLaunchKernelGGL(edge_gemm4, dim3(256), dim3(1024), 0, stream,
                           node_ab, ssrc, table, w2h + (size_t)l * 65536, b1s[l], aggs[l]);
        if (l < 4)
            hipLaunchKernelGGL(k_node, dim3(252), dim3(256), 0, stream,
                               aggs[l], wnode + (size_t)(l + 1) * 131072, b0s[l + 1], node_ab);
    }
}

// Round 13
// 240.104 us; speedup vs baseline: 1.0961x; 1.0961x over previous
//
#include <hip/hip_runtime.h>

#define NN 1000
#define NE 64000
#define HH 256

typedef _Float16 half8 __attribute__((ext_vector_type(8)));
typedef float floatx4 __attribute__((ext_vector_type(4)));

struct PrepArgs { const float* w0[5]; const float* w1[5]; };

// ---------------------------------------------------------------------------
// Pipeline (11 dispatches). In-kernel cross-block sync BANNED (r1: ~110 µs,
// r4: ~115 µs). r12 lesson: 1 block/CU + wide barriers kills overlap — keep
// >=4 independent blocks/CU.
//   1. k_pre1    : hist (16 private regions) || layer-0 node GEMM || chores
//   2. k_scatter2: replicated scan + counting-sort scatter + CHUNK TABLE
//   3..11. 5 x edge_gemm5 (+ 4 x k_node interleaved)
// edge_gemm5 (r13): 512 threads (8 waves) per 64-edge chunk, 32 KB h1 ->
// 4 blocks/CU x 8 waves = 32 waves/CU (FULL occupancy, vs r11's 16).
// r2 counters showed the edge family at Occupancy 36%, MfmaUtil 5%,
// VALUBusy 9% = latency-bound -> more resident waves is the lever.
// Same h1 values/swizzle, same W2 bytes re-indexed, same sole/split
// epilogue -> bit-identical numerics to r11.
// ---------------------------------------------------------------------------

// C = X[M,Kd] @ Wn^T, 16x128 tile per block (252 tiles); Wn in fragment order.
template <int NK>
__device__ __forceinline__ void node_tile(const float* __restrict__ X,
                                          const _Float16* __restrict__ Wn,
                                          const float* __restrict__ b0,
                                          _Float16* __restrict__ out, int bid) {
    const int Kd = NK * 32;
    int t = threadIdx.x;
    int wave = t >> 6, lane = t & 63;
    int q = lane >> 4, mn = lane & 15;
    int m0 = (bid % 63) * 16;
    int n0 = (bid / 63) * 128 + wave * 32;
    int slice = (bid / 63) * 4 + wave;
    int rr = m0 + mn;
    if (rr >= NN) rr = NN - 1;

    half8 afa[NK];
    half8 bfa[NK][2];
#pragma unroll
    for (int kk = 0; kk < NK; kk++) {
        int ka = kk * 32 + q * 8;
        const float* p = X + (size_t)rr * Kd + ka;
        floatx4 x0 = *(const floatx4*)p;
        floatx4 x1 = *(const floatx4*)(p + 4);
        half8 aa;
#pragma unroll
        for (int j = 0; j < 4; j++) { aa[j] = (_Float16)x0[j]; aa[4 + j] = (_Float16)x1[j]; }
        afa[kk] = aa;
        bfa[kk][0] = *(const half8*)(Wn + (((slice * NK + kk) * 2 + 0) * 64 + lane) * 8);
        bfa[kk][1] = *(const half8*)(Wn + (((slice * NK + kk) * 2 + 1) * 64 + lane) * 8);
    }
    floatx4 acc[2] = {};
#pragma unroll
    for (int kk = 0; kk < NK; kk++) {
        acc[0] = __builtin_amdgcn_mfma_f32_16x16x32_f16(afa[kk], bfa[kk][0], acc[0], 0, 0, 0);
        acc[1] = __builtin_amdgcn_mfma_f32_16x16x32_f16(afa[kk], bfa[kk][1], acc[1], 0, 0, 0);
    }
#pragma unroll
    for (int nt = 0; nt < 2; nt++) {
        int col = n0 + nt * 16 + mn;
        float bias = (col < 256) ? b0[col] : 0.f;
#pragma unroll
        for (int r2 = 0; r2 < 4; r2++) {
            int orow = m0 + q * 4 + r2;
            if (orow < NN)
                out[(size_t)orow * 512 + col] = (_Float16)(acc[nt][r2] + bias);
        }
    }
}

// layer-0 node GEMM with IN-KERNEL fp32->fp16 fragment conversion from w0.
__device__ __forceinline__ void node_tile0(const float* __restrict__ X,
                                           const float* __restrict__ w0,
                                           const float* __restrict__ b0,
                                           _Float16* __restrict__ out, int bid) {
    const int NK = 4;
    const int Kd = 128;
    int t = threadIdx.x;
    int wave = t >> 6, lane = t & 63;
    int q = lane >> 4, mn = lane & 15;
    int m0 = (bid % 63) * 16;
    int n0 = (bid / 63) * 128 + wave * 32;
    int slice = (bid / 63) * 4 + wave;
    int rr = m0 + mn;
    if (rr >= NN) rr = NN - 1;

    half8 afa[NK];
    half8 bfa[NK][2];
#pragma unroll
    for (int kk = 0; kk < NK; kk++) {
        int ka = kk * 32 + q * 8;
        const float* p = X + (size_t)rr * Kd + ka;
        floatx4 x0 = *(const floatx4*)p;
        floatx4 x1 = *(const floatx4*)(p + 4);
        half8 aa;
#pragma unroll
        for (int j = 0; j < 4; j++) { aa[j] = (_Float16)x0[j]; aa[4 + j] = (_Float16)x1[j]; }
        afa[kk] = aa;
#pragma unroll
        for (int nt = 0; nt < 2; nt++) {
            int n = slice * 32 + nt * 16 + mn;
            int k = kk * 32 + q * 8;
            half8 bb;
            if (n < 256) {
                const float* pa = w0 + (size_t)n * 256 + k;
                floatx4 a0 = *(const floatx4*)pa;
                floatx4 a1 = *(const floatx4*)(pa + 4);
                floatx4 c0 = *(const floatx4*)(pa + 128);
                floatx4 c1 = *(const floatx4*)(pa + 132);
#pragma unroll
                for (int j = 0; j < 4; j++) {
                    bb[j] = (_Float16)(a0[j] - c0[j]);
                    bb[4 + j] = (_Float16)(a1[j] - c1[j]);
                }
            } else {
                const float* pb = w0 + (size_t)(n - 256) * 256 + 128 + k;
                floatx4 c0 = *(const floatx4*)pb;
                floatx4 c1 = *(const floatx4*)(pb + 4);
#pragma unroll
                for (int j = 0; j < 4; j++) {
                    bb[j] = (_Float16)c0[j];
                    bb[4 + j] = (_Float16)c1[j];
                }
            }
            bfa[kk][nt] = bb;
        }
    }
    floatx4 acc[2] = {};
#pragma unroll
    for (int kk = 0; kk < NK; kk++) {
        acc[0] = __builtin_amdgcn_mfma_f32_16x16x32_f16(afa[kk], bfa[kk][0], acc[0], 0, 0, 0);
        acc[1] = __builtin_amdgcn_mfma_f32_16x16x32_f16(afa[kk], bfa[kk][1], acc[1], 0, 0, 0);
    }
#pragma unroll
    for (int nt = 0; nt < 2; nt++) {
        int col = n0 + nt * 16 + mn;
        float bias = (col < 256) ? b0[col] : 0.f;
#pragma unroll
        for (int r2 = 0; r2 < 4; r2++) {
            int orow = m0 + q * 4 + r2;
            if (orow < NN)
                out[(size_t)orow * 512 + col] = (_Float16)(acc[nt][r2] + bias);
        }
    }
}

// ONE pre dispatch: hist (16 private regions) || layer-0 node GEMM || chores.
__global__ __launch_bounds__(256) void k_pre1(PrepArgs pa,
                                              const int* __restrict__ ei,
                                              const float* __restrict__ X,
                                              const float* __restrict__ b0_0,
                                              _Float16* __restrict__ node_ab,
                                              _Float16* wnode, _Float16* w2h,
                                              int* cnts16, int* cursor,
                                              float* agg0, float* dout) {
    int bid = blockIdx.x;
    int t = threadIdx.x;
    if (bid < 16) {
        int* my = cnts16 + bid * 1024;
        for (int i = t; i < 1024; i += 256) my[i] = 0;
        __syncthreads();
        for (int e = bid * 256 + t; e < NE; e += 16 * 256)
            atomicAdd(&my[ei[NE + e] & 1023], 1);
    } else if (bid < 16 + 252) {
        node_tile0(X, pa.w0[0], b0_0, node_ab, bid - 16);
    } else {
        int gtid = (bid - 268) * 256 + t;
        int gs = 256 * 256;
        for (int i = gtid; i < 1024; i += gs) cursor[i] = 0;
        for (int l = 1; l < 5; l++) {
            const float* w0 = pa.w0[l];
            _Float16* wn = wnode + l * 131072;
            for (int i = gtid; i < 131072; i += gs) {
                int j = i & 7;
                int lane = (i >> 3) & 63;
                int nt = (i >> 9) & 1;
                int kk = (i >> 10) & 7;
                int slice = i >> 13;
                int mn = lane & 15, q = lane >> 4;
                int n = slice * 32 + nt * 16 + mn;
                int k = kk * 32 + q * 8 + j;
                float v = (n < 256) ? (w0[n * 512 + k] - w0[n * 512 + 256 + k])
                                    : w0[(n - 256) * 512 + 256 + k];
                wn[i] = (_Float16)v;
            }
        }
        for (int l = 0; l < 5; l++) {
            const float* w1 = pa.w1[l];
            _Float16* w2 = w2h + l * 65536;
            for (int i = gtid; i < 65536; i += gs) {
                int j = i & 7;
                int lane = (i >> 3) & 63;
                int nt = (i >> 9) & 3;
                int kk = (i >> 11) & 7;
                int ws = (i >> 14) & 3;
                int mn = lane & 15, q = lane >> 4;
                int row = ws * 64 + nt * 16 + mn;
                int col = kk * 32 + q * 8 + j;
                w2[i] = (_Float16)w1[row * 256 + col];
            }
        }
        floatx4 z = {0.f, 0.f, 0.f, 0.f};
        floatx4* p4 = (floatx4*)agg0;
        for (int i = gtid; i < 4 * NN * HH / 4; i += gs) p4[i] = z;
        floatx4* o4 = (floatx4*)dout;
        for (int i = gtid; i < NN * HH / 4; i += gs) o4[i] = z;
    }
}

// Replicated scan (sums 16 hist regions) + counting-sort scatter (src only).
// Block 0 additionally builds the chunk table: one int4 {dst, start, len,
// sole} per (dst, <=64 edges) chunk; tail entries zeroed (len=0).
__global__ __launch_bounds__(256) void k_scatter2(const int* __restrict__ ei,
                                                  const int* __restrict__ cnts16,
                                                  int* __restrict__ cursor,
                                                  int* __restrict__ ssrc,
                                                  int4* __restrict__ table) {
    __shared__ int sbase[1024];
    __shared__ int ssum[256];
    __shared__ int schk[256];
    int t = threadIdx.x;
    int base = t * 4;
    int c4[4]; int sum = 0;
#pragma unroll
    for (int j = 0; j < 4; j++) {
        int c = 0;
#pragma unroll
        for (int b = 0; b < 16; b++) c += cnts16[b * 1024 + base + j];
        c4[j] = c; sum += c;
    }
    ssum[t] = sum;
    int ch4[4]; int csum = 0;
#pragma unroll
    for (int j = 0; j < 4; j++) { ch4[j] = (c4[j] + 63) >> 6; csum += ch4[j]; }
    schk[t] = csum;
    __syncthreads();
    for (int d = 1; d < 256; d <<= 1) {
        int v1 = (t >= d) ? ssum[t - d] : 0;
        int v2 = (t >= d) ? schk[t - d] : 0;
        __syncthreads();
        ssum[t] += v1;
        schk[t] += v2;
        __syncthreads();
    }
    int run = (t > 0) ? ssum[t - 1] : 0;
#pragma unroll
    for (int j = 0; j < 4; j++) { sbase[base + j] = run; run += c4[j]; }
    __syncthreads();
    if (blockIdx.x == 0) {
        int crun = (t > 0) ? schk[t - 1] : 0;
#pragma unroll
        for (int j = 0; j < 4; j++) {
            int d = base + j, c = c4[j], st = sbase[base + j], nc = ch4[j];
            for (int k = 0; k < nc; k++) {
                int len = c - k * 64; if (len > 64) len = 64;
                table[crun + k] = make_int4(d, st + k * 64, len, nc == 1 ? 1 : 0);
            }
            crun += nc;
        }
        int nch = schk[255];
        for (int i = nch + t; i < 2048; i += 256) table[i] = make_int4(0, 0, 0, 0);
    }
    for (int e = blockIdx.x * 256 + t; e < NE; e += gridDim.x * 256) {
        int s = ei[e] & 1023, d = ei[NE + e] & 1023;
        int pos = sbase[d] + atomicAdd(&cursor[d], 1);
        if (pos < NE) ssrc[pos] = s;
    }
}

// pure node GEMM layer l+1 (reads agg_in), 252 blocks
__global__ __launch_bounds__(256) void k_node(const float* __restrict__ agg_in,
                                              const _Float16* __restrict__ Wn,
                                              const float* __restrict__ b0,
                                              _Float16* __restrict__ out) {
    node_tile<8>(agg_in, Wn, b0, out, blockIdx.x);
}

// r13: 512 threads (8 waves) per 64-edge chunk. Wave w owns 32 output cols
// (acc[4][2]); af/bf interleaved per-mt keeps VGPR < 64 so 8 waves/SIMD fit.
// 4 blocks/CU x 8 waves = 32 waves/CU. h1 values/swizzle identical to r11.
__global__ __launch_bounds__(512, 8) void edge_gemm5(const _Float16* __restrict__ node_ab,
                          const int* __restrict__ ssrc,
                          const int4* __restrict__ table,
                          const _Float16* __restrict__ W2,
                          const float* __restrict__ b2,
                          float* __restrict__ agg) {
    __shared__ _Float16 h1[64 * 256];
    int4 ck = table[blockIdx.x];
    int len = ck.z;
    if (len == 0) return;
    int dst = ck.x, start = ck.y, sole = ck.w;
    int t = threadIdx.x;
    int wave = t >> 6, lane = t & 63;
    int q = lane >> 4, mn = lane & 15;
    // wave's 32-col W2 fragment slice base (same prep bytes, re-indexed)
    const _Float16* W2w = W2 + (wave >> 1) * 16384 + ((wave & 1) * 2) * 512;

    {   // staging: 512 threads = 16 rows x 32 slots per iteration, 4 iterations
        int s = t & 31;          // 16-B slot within the 256-half half-row
        int rg = t >> 5;         // rowgroup 0..15
        half8 av = *(const half8*)(node_ab + (size_t)dst * 512 + s * 8);  // once
#pragma unroll
        for (int it = 0; it < 4; it++) {
            int row = it * 16 + rg;
            half8 hv = {};
            if (row < len) {
                int sn = ssrc[start + row];       // 32-lane broadcast load
                half8 bv = *(const half8*)(node_ab + (size_t)sn * 512 + 256 + s * 8);
                hv = av + bv;
#pragma unroll
                for (int j = 0; j < 8; j++) hv[j] = hv[j] > (_Float16)0 ? hv[j] : (_Float16)0;
            }
            int p = (s & ~7) | ((s ^ row) & 7);   // XOR swizzle, c = s
            *(half8*)(&h1[row * 256 + p * 8]) = hv;
        }
    }
    __syncthreads();

    floatx4 acc[4][2] = {};
#pragma unroll
    for (int kk = 0; kk < 8; kk++) {
        half8 bf0 = *(const half8*)(W2w + kk * 2048 + (size_t)lane * 8);
        half8 bf1 = *(const half8*)(W2w + kk * 2048 + 512 + (size_t)lane * 8);
#pragma unroll
        for (int mt = 0; mt < 4; mt++) {
            int r = mt * 16 + mn;
            int c = kk * 4 + q;
            int p = (c & ~7) | ((c ^ r) & 7);
            half8 af = *(const half8*)(&h1[r * 256 + p * 8]);
            acc[mt][0] = __builtin_amdgcn_mfma_f32_16x16x32_f16(af, bf0, acc[mt][0], 0, 0, 0);
            acc[mt][1] = __builtin_amdgcn_mfma_f32_16x16x32_f16(af, bf1, acc[mt][1], 0, 0, 0);
        }
    }

    // masked per-thread max over valid rows, then reduce across the 4 q-lanes
    float m[2] = {-3.0e38f, -3.0e38f};
#pragma unroll
    for (int mt = 0; mt < 4; mt++) {
#pragma unroll
        for (int r2 = 0; r2 < 4; r2++) {
            int row = mt * 16 + q * 4 + r2;
            if (row < len) {
                m[0] = fmaxf(m[0], acc[mt][0][r2]);
                m[1] = fmaxf(m[1], acc[mt][1][r2]);
            }
        }
    }
#pragma unroll
    for (int nt = 0; nt < 2; nt++) {
        m[nt] = fmaxf(m[nt], __shfl_xor(m[nt], 16, 64));
        m[nt] = fmaxf(m[nt], __shfl_xor(m[nt], 32, 64));
    }
    if (q == 0) {
#pragma unroll
        for (int nt = 0; nt < 2; nt++) {
            int col = wave * 32 + nt * 16 + mn;
            float v = m[nt] + b2[col];
            v = v > 0.f ? v : 0.f;
            float* p = agg + (size_t)dst * HH + col;
            if (sole) {
                *p = v;                               // block-exclusive row
            } else if (v > 0.f) {
                atomicMax((unsigned int*)p, __float_as_uint(v));  // agg pre-zeroed
            }
        }
    }
}

extern "C" void kernel_launch(void* const* d_in, const int* in_sizes, int n_in,
                              void* d_out, int out_size, void* d_ws, size_t ws_size,
                              hipStream_t stream) {
    const float* x = (const float*)d_in[0];
    const int* ei = (const int*)d_in[1];  // int32 per harness contract
    PrepArgs pa;
    const float* b0s[5];
    const float* b1s[5];
    for (int l = 0; l < 5; l++) {
        pa.w0[l] = (const float*)d_in[2 + 4 * l];
        b0s[l] = (const float*)d_in[3 + 4 * l];
        pa.w1[l] = (const float*)d_in[4 + 4 * l];
        b1s[l] = (const float*)d_in[5 + 4 * l];
    }

    int* ssrc = (int*)d_ws;                              // 64000 ints
    int* cnts16 = ssrc + NE;                             // 16 x 1024 ints
    int* cursor = cnts16 + 16 * 1024;                    // 1024 ints
    int4* table = (int4*)(cursor + 1024);                // 2048 int4 (32 KB)
    _Float16* node_ab = (_Float16*)(table + 2048);       // [1024][512] fp16, 1 MB
    float* agg0 = (float*)(node_ab + 1024 * 512);        // 4 x 1 MB (contiguous)
    float* agg1 = agg0 + NN * HH;
    float* agg2 = agg1 + NN * HH;
    float* agg3 = agg2 + NN * HH;
    _Float16* wnode = (_Float16*)(agg3 + NN * HH);       // 5 x 131072 halfs (slot 0 unused)
    _Float16* w2h = wnode + 5 * 131072;                  // 5 x 65536 halfs

    hipLaunchKernelGGL(k_pre1, dim3(524), dim3(256), 0, stream,
                       pa, ei, x, b0s[0], node_ab, wnode, w2h,
                       cnts16, cursor, agg0, (float*)d_out);
    hipLaunchKernelGGL(k_scatter2, dim3(NE / 256), dim3(256), 0, stream,
                       ei, cnts16, cursor, ssrc, table);

    float* aggs[5] = {agg0, agg1, agg2, agg3, (float*)d_out};
    for (int l = 0; l < 5; l++) {
        hipLaunchKernelGGL(edge_gemm5, dim3(2048), dim3(512), 0, stream,
                           node_ab, ssrc, table, w2h + (size_t)l * 65536, b1s[l], aggs[l]);
        if (l < 4)
            hipLaunchKernelGGL(k_node, dim3(252), dim3(256), 0, stream,
                               aggs[l], wnode + (size_t)(l + 1) * 131072, b0s[l + 1], node_ab);
    }
}

// Round 14
// 234.208 us; speedup vs baseline: 1.1237x; 1.0252x over previous
//
#include <hip/hip_runtime.h>

#define NN 1000
#define NE 64000
#define HH 256

typedef _Float16 half8 __attribute__((ext_vector_type(8)));
typedef float floatx4 __attribute__((ext_vector_type(4)));

struct PrepArgs { const float* w0[5]; const float* w1[5]; };

// ---------------------------------------------------------------------------
// Pipeline (11 dispatches; boundary ~2 µs. In-kernel cross-block sync BANNED:
// grid.sync ~110 µs (r1), threadfence flag-barrier ~115 µs (r4)).
//   1. k_pre1    : hist (16 private regions) || layer-0 node GEMM (in-kernel
//                  weight conversion) || chores (swizzles + zeroing)
//   2. k_scatter2: replicated scan + counting-sort scatter + CHUNK TABLE:
//                  one entry per (dst, <=64 edges) chunk (block 0 writes it)
//   3..11. 5 x edge_gemm3 (+ 4 x k_node interleaved)
// edge_gemm3: block = ONE dst chunk. dst uniform -> a-row loaded once per
// lane; coalesced b-gather; padded rows masked in-register. Epilogue =
// masked reg-max + 2 shfl_xor over q-lanes -> one coalesced store per
// thread. Sole-chunk dsts: plain store, zero atomics. Split dsts: atomicMax.
// relu(max+bias)=max(relu(acc_i+bias)) exact by monotone fp32 rounding.
//
// FINAL (r14 = r11 verbatim, best measured 234.3 µs): edge kernels are
// latency-chain-bound at ~28 µs across all tested organizations (L1-line,
// W2-streaming, occupancy theories each measured; r12/r13 regressed).
// Floor = 40 µs harness fill + latency-bound edge dispatches + boundaries.
// ---------------------------------------------------------------------------

// C = X[M,Kd] @ Wn^T, 16x128 tile per block (252 tiles); Wn in fragment order.
template <int NK>
__device__ __forceinline__ void node_tile(const float* __restrict__ X,
                                          const _Float16* __restrict__ Wn,
                                          const float* __restrict__ b0,
                                          _Float16* __restrict__ out, int bid) {
    const int Kd = NK * 32;
    int t = threadIdx.x;
    int wave = t >> 6, lane = t & 63;
    int q = lane >> 4, mn = lane & 15;
    int m0 = (bid % 63) * 16;
    int n0 = (bid / 63) * 128 + wave * 32;
    int slice = (bid / 63) * 4 + wave;
    int rr = m0 + mn;
    if (rr >= NN) rr = NN - 1;

    half8 afa[NK];
    half8 bfa[NK][2];
#pragma unroll
    for (int kk = 0; kk < NK; kk++) {
        int ka = kk * 32 + q * 8;
        const float* p = X + (size_t)rr * Kd + ka;
        floatx4 x0 = *(const floatx4*)p;
        floatx4 x1 = *(const floatx4*)(p + 4);
        half8 aa;
#pragma unroll
        for (int j = 0; j < 4; j++) { aa[j] = (_Float16)x0[j]; aa[4 + j] = (_Float16)x1[j]; }
        afa[kk] = aa;
        bfa[kk][0] = *(const half8*)(Wn + (((slice * NK + kk) * 2 + 0) * 64 + lane) * 8);
        bfa[kk][1] = *(const half8*)(Wn + (((slice * NK + kk) * 2 + 1) * 64 + lane) * 8);
    }
    floatx4 acc[2] = {};
#pragma unroll
    for (int kk = 0; kk < NK; kk++) {
        acc[0] = __builtin_amdgcn_mfma_f32_16x16x32_f16(afa[kk], bfa[kk][0], acc[0], 0, 0, 0);
        acc[1] = __builtin_amdgcn_mfma_f32_16x16x32_f16(afa[kk], bfa[kk][1], acc[1], 0, 0, 0);
    }
#pragma unroll
    for (int nt = 0; nt < 2; nt++) {
        int col = n0 + nt * 16 + mn;
        float bias = (col < 256) ? b0[col] : 0.f;
#pragma unroll
        for (int r2 = 0; r2 < 4; r2++) {
            int orow = m0 + q * 4 + r2;
            if (orow < NN)
                out[(size_t)orow * 512 + col] = (_Float16)(acc[nt][r2] + bias);
        }
    }
}

// layer-0 node GEMM with IN-KERNEL fp32->fp16 fragment conversion from w0.
__device__ __forceinline__ void node_tile0(const float* __restrict__ X,
                                           const float* __restrict__ w0,
                                           const float* __restrict__ b0,
                                           _Float16* __restrict__ out, int bid) {
    const int NK = 4;
    const int Kd = 128;
    int t = threadIdx.x;
    int wave = t >> 6, lane = t & 63;
    int q = lane >> 4, mn = lane & 15;
    int m0 = (bid % 63) * 16;
    int n0 = (bid / 63) * 128 + wave * 32;
    int slice = (bid / 63) * 4 + wave;
    int rr = m0 + mn;
    if (rr >= NN) rr = NN - 1;

    half8 afa[NK];
    half8 bfa[NK][2];
#pragma unroll
    for (int kk = 0; kk < NK; kk++) {
        int ka = kk * 32 + q * 8;
        const float* p = X + (size_t)rr * Kd + ka;
        floatx4 x0 = *(const floatx4*)p;
        floatx4 x1 = *(const floatx4*)(p + 4);
        half8 aa;
#pragma unroll
        for (int j = 0; j < 4; j++) { aa[j] = (_Float16)x0[j]; aa[4 + j] = (_Float16)x1[j]; }
        afa[kk] = aa;
#pragma unroll
        for (int nt = 0; nt < 2; nt++) {
            int n = slice * 32 + nt * 16 + mn;
            int k = kk * 32 + q * 8;
            half8 bb;
            if (n < 256) {
                const float* pa = w0 + (size_t)n * 256 + k;
                floatx4 a0 = *(const floatx4*)pa;
                floatx4 a1 = *(const floatx4*)(pa + 4);
                floatx4 c0 = *(const floatx4*)(pa + 128);
                floatx4 c1 = *(const floatx4*)(pa + 132);
#pragma unroll
                for (int j = 0; j < 4; j++) {
                    bb[j] = (_Float16)(a0[j] - c0[j]);
                    bb[4 + j] = (_Float16)(a1[j] - c1[j]);
                }
            } else {
                const float* pb = w0 + (size_t)(n - 256) * 256 + 128 + k;
                floatx4 c0 = *(const floatx4*)pb;
                floatx4 c1 = *(const floatx4*)(pb + 4);
#pragma unroll
                for (int j = 0; j < 4; j++) {
                    bb[j] = (_Float16)c0[j];
                    bb[4 + j] = (_Float16)c1[j];
                }
            }
            bfa[kk][nt] = bb;
        }
    }
    floatx4 acc[2] = {};
#pragma unroll
    for (int kk = 0; kk < NK; kk++) {
        acc[0] = __builtin_amdgcn_mfma_f32_16x16x32_f16(afa[kk], bfa[kk][0], acc[0], 0, 0, 0);
        acc[1] = __builtin_amdgcn_mfma_f32_16x16x32_f16(afa[kk], bfa[kk][1], acc[1], 0, 0, 0);
    }
#pragma unroll
    for (int nt = 0; nt < 2; nt++) {
        int col = n0 + nt * 16 + mn;
        float bias = (col < 256) ? b0[col] : 0.f;
#pragma unroll
        for (int r2 = 0; r2 < 4; r2++) {
            int orow = m0 + q * 4 + r2;
            if (orow < NN)
                out[(size_t)orow * 512 + col] = (_Float16)(acc[nt][r2] + bias);
        }
    }
}

// ONE pre dispatch: hist (16 private regions) || layer-0 node GEMM || chores.
__global__ __launch_bounds__(256) void k_pre1(PrepArgs pa,
                                              const int* __restrict__ ei,
                                              const float* __restrict__ X,
                                              const float* __restrict__ b0_0,
                                              _Float16* __restrict__ node_ab,
                                              _Float16* wnode, _Float16* w2h,
                                              int* cnts16, int* cursor,
                                              float* agg0, float* dout) {
    int bid = blockIdx.x;
    int t = threadIdx.x;
    if (bid < 16) {
        int* my = cnts16 + bid * 1024;
        for (int i = t; i < 1024; i += 256) my[i] = 0;
        __syncthreads();
        for (int e = bid * 256 + t; e < NE; e += 16 * 256)
            atomicAdd(&my[ei[NE + e] & 1023], 1);
    } else if (bid < 16 + 252) {
        node_tile0(X, pa.w0[0], b0_0, node_ab, bid - 16);
    } else {
        int gtid = (bid - 268) * 256 + t;
        int gs = 256 * 256;
        for (int i = gtid; i < 1024; i += gs) cursor[i] = 0;
        for (int l = 1; l < 5; l++) {
            const float* w0 = pa.w0[l];
            _Float16* wn = wnode + l * 131072;
            for (int i = gtid; i < 131072; i += gs) {
                int j = i & 7;
                int lane = (i >> 3) & 63;
                int nt = (i >> 9) & 1;
                int kk = (i >> 10) & 7;
                int slice = i >> 13;
                int mn = lane & 15, q = lane >> 4;
                int n = slice * 32 + nt * 16 + mn;
                int k = kk * 32 + q * 8 + j;
                float v = (n < 256) ? (w0[n * 512 + k] - w0[n * 512 + 256 + k])
                                    : w0[(n - 256) * 512 + 256 + k];
                wn[i] = (_Float16)v;
            }
        }
        for (int l = 0; l < 5; l++) {
            const float* w1 = pa.w1[l];
            _Float16* w2 = w2h + l * 65536;
            for (int i = gtid; i < 65536; i += gs) {
                int j = i & 7;
                int lane = (i >> 3) & 63;
                int nt = (i >> 9) & 3;
                int kk = (i >> 11) & 7;
                int ws = (i >> 14) & 3;
                int mn = lane & 15, q = lane >> 4;
                int row = ws * 64 + nt * 16 + mn;
                int col = kk * 32 + q * 8 + j;
                w2[i] = (_Float16)w1[row * 256 + col];
            }
        }
        floatx4 z = {0.f, 0.f, 0.f, 0.f};
        floatx4* p4 = (floatx4*)agg0;
        for (int i = gtid; i < 4 * NN * HH / 4; i += gs) p4[i] = z;
        floatx4* o4 = (floatx4*)dout;
        for (int i = gtid; i < NN * HH / 4; i += gs) o4[i] = z;
    }
}

// Replicated scan (sums 16 hist regions) + counting-sort scatter (src only).
// Block 0 additionally builds the chunk table: one int4 {dst, start, len,
// sole} per (dst, <=64 edges) chunk; tail entries zeroed (len=0).
__global__ __launch_bounds__(256) void k_scatter2(const int* __restrict__ ei,
                                                  const int* __restrict__ cnts16,
                                                  int* __restrict__ cursor,
                                                  int* __restrict__ ssrc,
                                                  int4* __restrict__ table) {
    __shared__ int sbase[1024];
    __shared__ int ssum[256];
    __shared__ int schk[256];
    int t = threadIdx.x;
    int base = t * 4;
    int c4[4]; int sum = 0;
#pragma unroll
    for (int j = 0; j < 4; j++) {
        int c = 0;
#pragma unroll
        for (int b = 0; b < 16; b++) c += cnts16[b * 1024 + base + j];
        c4[j] = c; sum += c;
    }
    ssum[t] = sum;
    // chunk counts (second scan array filled before scans run)
    int ch4[4]; int csum = 0;
#pragma unroll
    for (int j = 0; j < 4; j++) { ch4[j] = (c4[j] + 63) >> 6; csum += ch4[j]; }
    schk[t] = csum;
    __syncthreads();
    for (int d = 1; d < 256; d <<= 1) {
        int v1 = (t >= d) ? ssum[t - d] : 0;
        int v2 = (t >= d) ? schk[t - d] : 0;
        __syncthreads();
        ssum[t] += v1;
        schk[t] += v2;
        __syncthreads();
    }
    int run = (t > 0) ? ssum[t - 1] : 0;
#pragma unroll
    for (int j = 0; j < 4; j++) { sbase[base + j] = run; run += c4[j]; }
    __syncthreads();
    if (blockIdx.x == 0) {
        int crun = (t > 0) ? schk[t - 1] : 0;
#pragma unroll
        for (int j = 0; j < 4; j++) {
            int d = base + j, c = c4[j], st = sbase[base + j], nc = ch4[j];
            for (int k = 0; k < nc; k++) {
                int len = c - k * 64; if (len > 64) len = 64;
                table[crun + k] = make_int4(d, st + k * 64, len, nc == 1 ? 1 : 0);
            }
            crun += nc;
        }
        int nch = schk[255];
        for (int i = nch + t; i < 2048; i += 256) table[i] = make_int4(0, 0, 0, 0);
    }
    for (int e = blockIdx.x * 256 + t; e < NE; e += gridDim.x * 256) {
        int s = ei[e] & 1023, d = ei[NE + e] & 1023;
        int pos = sbase[d] + atomicAdd(&cursor[d], 1);
        if (pos < NE) ssrc[pos] = s;
    }
}

// pure node GEMM layer l+1 (reads agg_in), 252 blocks
__global__ __launch_bounds__(256) void k_node(const float* __restrict__ agg_in,
                                              const _Float16* __restrict__ Wn,
                                              const float* __restrict__ b0,
                                              _Float16* __restrict__ out) {
    node_tile<8>(agg_in, Wn, b0, out, blockIdx.x);
}

// ONE dst chunk per block (<=64 edges, dst uniform). Coalesced staging:
// a-row loaded once per lane; b rows gathered 512-B-coalesced; pad rows -> 0.
// MFMA vs fragment-ordered W2 -> acc[4][4]; masked reg-max + 2 shfl_xor ->
// relu(max+bias); sole chunk: plain coalesced store; split: atomicMax.
__global__ __launch_bounds__(256, 4) void edge_gemm3(const _Float16* __restrict__ node_ab,
                          const int* __restrict__ ssrc,
                          const int4* __restrict__ table,
                          const _Float16* __restrict__ W2,
                          const float* __restrict__ b2,
                          float* __restrict__ agg) {
    __shared__ _Float16 h1[64 * 256];
    __shared__ int ssd[64];
    int4 ck = table[blockIdx.x];
    int len = ck.z;
    if (len == 0) return;
    int dst = ck.x, start = ck.y, sole = ck.w;
    int t = threadIdx.x;
    int wave = t >> 6, lane = t & 63;
    int q = lane >> 4, mn = lane & 15;
    const _Float16* W2w = W2 + wave * 16384;

    if (t < 64) ssd[t] = (t < len) ? ssrc[start + t] : 0;
    __syncthreads();
    {
        int s = lane & 31;       // 16-B slot within the 256-half half-row
        int rh = lane >> 5;
        half8 av = *(const half8*)(node_ab + (size_t)dst * 512 + s * 8);  // once
#pragma unroll
        for (int it = 0; it < 8; it++) {
            int row = it * 8 + wave * 2 + rh;          // bijective over 0..63
            half8 hv = {};
            if (row < len) {
                int sn = ssd[row];
                half8 bv = *(const half8*)(node_ab + (size_t)sn * 512 + 256 + s * 8);
                hv = av + bv;
#pragma unroll
                for (int j = 0; j < 8; j++) hv[j] = hv[j] > (_Float16)0 ? hv[j] : (_Float16)0;
            }
            int p = (s & ~7) | ((s ^ row) & 7);        // XOR swizzle, c = s
            *(half8*)(&h1[row * 256 + p * 8]) = hv;
        }
    }
    __syncthreads();

    floatx4 acc[4][4] = {};
#pragma unroll
    for (int kk = 0; kk < 8; kk++) {
        half8 bf[4];
#pragma unroll
        for (int nt = 0; nt < 4; nt++)
            bf[nt] = *(const half8*)(W2w + (kk * 4 + nt) * 512 + lane * 8);  // coalesced
        half8 af[4];
#pragma unroll
        for (int mt = 0; mt < 4; mt++) {
            int r = mt * 16 + mn;
            int c = kk * 4 + q;
            int p = (c & ~7) | ((c ^ r) & 7);
            af[mt] = *(const half8*)(&h1[r * 256 + p * 8]);
        }
#pragma unroll
        for (int mt = 0; mt < 4; mt++)
#pragma unroll
            for (int nt = 0; nt < 4; nt++)
                acc[mt][nt] = __builtin_amdgcn_mfma_f32_16x16x32_f16(af[mt], bf[nt], acc[mt][nt], 0, 0, 0);
    }

    // masked per-thread max over valid rows, then reduce across the 4 q-lanes
    float m[4] = {-3.0e38f, -3.0e38f, -3.0e38f, -3.0e38f};
#pragma unroll
    for (int mt = 0; mt < 4; mt++) {
#pragma unroll
        for (int r2 = 0; r2 < 4; r2++) {
            int row = mt * 16 + q * 4 + r2;
            if (row < len) {
#pragma unroll
                for (int nt = 0; nt < 4; nt++) m[nt] = fmaxf(m[nt], acc[mt][nt][r2]);
            }
        }
    }
#pragma unroll
    for (int nt = 0; nt < 4; nt++) {
        m[nt] = fmaxf(m[nt], __shfl_xor(m[nt], 16, 64));
        m[nt] = fmaxf(m[nt], __shfl_xor(m[nt], 32, 64));
    }
    // lane writes col = wave*64 + q*16 + mn  (256 coalesced cols per block)
    float v = (q == 0) ? m[0] : (q == 1) ? m[1] : (q == 2) ? m[2] : m[3];
    int col = wave * 64 + q * 16 + mn;
    v = v + b2[col];
    v = v > 0.f ? v : 0.f;
    float* p = agg + (size_t)dst * HH + col;
    if (sole) {
        *p = v;                                        // block-exclusive row
    } else if (v > 0.f) {
        atomicMax((unsigned int*)p, __float_as_uint(v));  // agg pre-zeroed
    }
}

extern "C" void kernel_launch(void* const* d_in, const int* in_sizes, int n_in,
                              void* d_out, int out_size, void* d_ws, size_t ws_size,
                              hipStream_t stream) {
    const float* x = (const float*)d_in[0];
    const int* ei = (const int*)d_in[1];  // int32 per harness contract
    PrepArgs pa;
    const float* b0s[5];
    const float* b1s[5];
    for (int l = 0; l < 5; l++) {
        pa.w0[l] = (const float*)d_in[2 + 4 * l];
        b0s[l] = (const float*)d_in[3 + 4 * l];
        pa.w1[l] = (const float*)d_in[4 + 4 * l];
        b1s[l] = (const float*)d_in[5 + 4 * l];
    }

    int* ssrc = (int*)d_ws;                              // 64000 ints
    int* cnts16 = ssrc + NE;                             // 16 x 1024 ints
    int* cursor = cnts16 + 16 * 1024;                    // 1024 ints
    int4* table = (int4*)(cursor + 1024);                // 2048 int4 (32 KB)
    _Float16* node_ab = (_Float16*)(table + 2048);       // [1024][512] fp16, 1 MB
    float* agg0 = (float*)(node_ab + 1024 * 512);        // 4 x 1 MB (contiguous)
    float* agg1 = agg0 + NN * HH;
    float* agg2 = agg1 + NN * HH;
    float* agg3 = agg2 + NN * HH;
    _Float16* wnode = (_Float16*)(agg3 + NN * HH);       // 5 x 131072 halfs (slot 0 unused)
    _Float16* w2h = wnode + 5 * 131072;                  // 5 x 65536 halfs

    hipLaunchKernelGGL(k_pre1, dim3(524), dim3(256), 0, stream,
                       pa, ei, x, b0s[0], node_ab, wnode, w2h,
                       cnts16, cursor, agg0, (float*)d_out);
    hipLaunchKernelGGL(k_scatter2, dim3(NE / 256), dim3(256), 0, stream,
                       ei, cnts16, cursor, ssrc, table);

    float* aggs[5] = {agg0, agg1, agg2, agg3, (float*)d_out};
    for (int l = 0; l < 5; l++) {
        hipLaunchKernelGGL(edge_gemm3, dim3(2048), dim3(256), 0, stream,
                           node_ab, ssrc, table, w2h + (size_t)l * 65536, b1s[l], aggs[l]);
        if (l < 4)
            hipLaunchKernelGGL(k_node, dim3(252), dim3(256), 0, stream,
                               aggs[l], wnode + (size_t)(l + 1) * 131072, b0s[l + 1], node_ab);
    }
}